// Round 3
// baseline (251.179 us; speedup 1.0000x reference)
//
#include <hip/hip_runtime.h>
#include <stdint.h>

typedef __attribute__((ext_vector_type(8))) __bf16 bf16x8;
typedef __attribute__((ext_vector_type(4))) float f32x4;

#define SEQ 2048

// ---------- ws layout (bytes) ----------
// HS2 region [0, 16MB) is dead after the QKV GEMM; VT and AO overlay it.
#define OFF_HS2   0ull               // bf16 [8192][1024]  ([hi|lo] along K)
#define OFF_VT    0ull               // bf16 [32][64][2048]   (overlay, after GEMM)
#define OFF_AO    8388608ull         // bf16 [8192][512]      (overlay, after GEMM)
#define OFF_WQKV2 16777216ull        // bf16 [1536][1536]  (w_t[n][k'], k'=[hi|hi|lo])
#define OFF_WO    21495808ull        // bf16 [512][512]
#define OFF_QH    22020096ull        // bf16 [32][2048][64]
#define OFF_QL    30408704ull
#define OFF_K     38797312ull
#define OFF_V     47185920ull
#define OFF_BIAS  55574528ull        // f32 [8][4096]
// total 55,705,600 bytes (~53.1 MB)

__device__ __forceinline__ int swz(int row) { return ((row & 7) << 4) ^ ((row & 8) << 1); }

__device__ __forceinline__ void gl_lds16(const void* g, void* l) {
  __builtin_amdgcn_global_load_lds(
      (__attribute__((address_space(1))) void*)(uintptr_t)g,
      (__attribute__((address_space(3))) void*)(uint32_t)(uintptr_t)l, 16, 0, 0);
}

// ---------- prep: hidden_states f32 -> [hi|lo] bf16, K' = 1024 ----------
__global__ void k_cast_hs2(const float* __restrict__ hs, __bf16* __restrict__ out) {
  int gid = blockIdx.x * 256 + threadIdx.x;       // 8192*1024/8 threads
  int row = gid >> 7, c8 = (gid & 127) * 8;
  int src = (c8 < 512) ? c8 : c8 - 512;
  const float* p = hs + (size_t)row * 512 + src;
  float4 a = *(const float4*)p, b = *(const float4*)(p + 4);
  float v[8] = {a.x, a.y, a.z, a.w, b.x, b.y, b.z, b.w};
  bf16x8 o;
  if (c8 < 512) {
#pragma unroll
    for (int j = 0; j < 8; ++j) o[j] = (__bf16)v[j];
  } else {
#pragma unroll
    for (int j = 0; j < 8; ++j) { __bf16 h = (__bf16)v[j]; o[j] = (__bf16)(v[j] - (float)h); }
  }
  *(bf16x8*)(out + (size_t)row * 1024 + c8) = o;
}

// ---------- prep: QKV weights -> transposed split [1536][1536] ----------
__global__ void k_prep_w2(const float* __restrict__ Wq, const float* __restrict__ Wk,
                          const float* __restrict__ Wv, __bf16* __restrict__ w2) {
  int idx = blockIdx.x * 256 + threadIdx.x;       // 1536*1536
  int n = idx / 1536, kp = idx - n * 1536;
  const float* W = (n < 512) ? Wq : (n < 1024) ? Wk : Wv;
  int nn = n & 511;
  int k = (kp < 512) ? kp : (kp < 1024) ? kp - 512 : kp - 1024;
  float w = W[(size_t)k * 512 + nn];
  __bf16 h = (__bf16)w;
  w2[idx] = (kp < 1024) ? h : (__bf16)(w - (float)h);
}

__global__ void k_prep_wo(const float* __restrict__ Wo, __bf16* __restrict__ wo_t) {
  int idx = blockIdx.x * 256 + threadIdx.x;       // 512*512
  int n = idx >> 9, k = idx & 511;
  wo_t[idx] = (__bf16)Wo[(size_t)k * 512 + n];
}

// ---------- prep: T5 relative-position bias table ----------
// bucket thresholds derived from exact math of 8+int(log(rp/8)/log(16)*8):
// v = #{12,16,23,32,46,64,91} <= rp  (agrees with f32 reference at rp=16/32/64)
__global__ void k_bias(const float* __restrict__ rel_bias, float* __restrict__ bias_tab) {
  int idx = blockIdx.x * 256 + threadIdx.x;       // 8*4096
  int h = idx >> 12, dIdx = idx & 4095;
  float v = 0.f;
  if (dIdx < 4095) {
    int d = dIdx - 2047;                          // d = k - q
    int rp = d < 0 ? -d : d;
    int bp;
    if (rp < 8) bp = rp;
    else bp = 8 + (rp >= 12) + (rp >= 16) + (rp >= 23) + (rp >= 32) + (rp >= 46) + (rp >= 64) + (rp >= 91);
    v = rel_bias[((d > 0 ? 16 : 0) + bp) * 8 + h];
  }
  bias_tab[idx] = v;
}

// ---------- GEMM: C[M][N] = A[M][K'] @ Bt[N][K']^T  (128x128 tile, 16x16x32 bf16) ----------
// MODE 0: QKV split-K' GEMM (KSTEPS=48; A physical K=1024, kt>=32 remaps to hi segment)
// MODE 1: output projection, f32 out (KSTEPS=16)
template <int MODE, int KSTEPS, int LDA, int LDB>
__global__ __launch_bounds__(256) void k_gemm(const __bf16* __restrict__ A,
                                              const __bf16* __restrict__ Bt,
                                              __bf16* __restrict__ qh, __bf16* __restrict__ ql,
                                              __bf16* __restrict__ ko, __bf16* __restrict__ vo,
                                              float* __restrict__ fo) {
  __shared__ __align__(16) __bf16 As[2][128 * 32];
  __shared__ __align__(16) __bf16 Bs[2][128 * 32];
  int tid = threadIdx.x, w = tid >> 6, l = tid & 63;
  int lr = l & 15, lh = l >> 4;
  int m0 = blockIdx.y * 128, n0 = blockIdx.x * 128;
  int wm = (w >> 1) * 64, wn = (w & 1) * 64;
  f32x4 zero4 = {0.f, 0.f, 0.f, 0.f};
  f32x4 acc[4][4];
#pragma unroll
  for (int i = 0; i < 4; ++i)
#pragma unroll
    for (int j = 0; j < 4; ++j) acc[i][j] = zero4;

  auto stage = [&](int kt, int buf) {
    int ka = (MODE == 0 && kt >= 32) ? kt - 32 : kt;
#pragma unroll
    for (int c = 0; c < 2; ++c) {
      int i = c * 256 + w * 64 + l;
      int row = i >> 2, cc = i & 3;
      gl_lds16(A + (size_t)(m0 + row) * LDA + ka * 32 + cc * 8,
               (char*)&As[buf][0] + (c * 256 + w * 64) * 16);
      gl_lds16(Bt + (size_t)(n0 + row) * LDB + kt * 32 + cc * 8,
               (char*)&Bs[buf][0] + (c * 256 + w * 64) * 16);
    }
  };

  stage(0, 0);
  __syncthreads();
  int cur = 0;
  for (int kt = 0; kt < KSTEPS; ++kt) {
    if (kt + 1 < KSTEPS) stage(kt + 1, cur ^ 1);
    bf16x8 af[4], bfr[4];
#pragma unroll
    for (int mi = 0; mi < 4; ++mi)
      af[mi] = *(const bf16x8*)&As[cur][(wm + mi * 16 + lr) * 32 + lh * 8];
#pragma unroll
    for (int ni = 0; ni < 4; ++ni)
      bfr[ni] = *(const bf16x8*)&Bs[cur][(wn + ni * 16 + lr) * 32 + lh * 8];
#pragma unroll
    for (int mi = 0; mi < 4; ++mi)
#pragma unroll
      for (int ni = 0; ni < 4; ++ni)
        acc[mi][ni] = __builtin_amdgcn_mfma_f32_16x16x32_bf16(af[mi], bfr[ni], acc[mi][ni], 0, 0, 0);
    __syncthreads();
    cur ^= 1;
  }

#pragma unroll
  for (int mi = 0; mi < 4; ++mi)
#pragma unroll
    for (int ni = 0; ni < 4; ++ni)
#pragma unroll
      for (int r = 0; r < 4; ++r) {
        int m = m0 + wm + mi * 16 + lh * 4 + r;
        int n = n0 + wn + ni * 16 + lr;
        float vv = acc[mi][ni][r];
        if (MODE == 0) {
          int which = n >> 9, c9 = n & 511, hh = c9 >> 6, dh = c9 & 63;
          int b = m >> 11, s = m & 2047;
          size_t o = (size_t)((b * 8 + hh) * 2048 + s) * 64 + dh;
          if (which == 0) {
            __bf16 hv = (__bf16)vv;
            qh[o] = hv;
            ql[o] = (__bf16)(vv - (float)hv);
          } else if (which == 1) {
            ko[o] = (__bf16)vv;
          } else {
            vo[o] = (__bf16)vv;
          }
        } else {
          fo[(size_t)m * 512 + n] = vv;
        }
      }
}

// ---------- transpose V to [bh][dh][s] ----------
__global__ void k_transv(const __bf16* __restrict__ v, __bf16* __restrict__ vt) {
  __shared__ __bf16 t[64][72];
  int bh = blockIdx.y, s0 = blockIdx.x * 64, tid = threadIdx.x;
  const __bf16* src = v + (size_t)bh * SEQ * 64;
  __bf16* dst = vt + (size_t)bh * 64 * SEQ;
#pragma unroll
  for (int c = 0; c < 2; ++c) {
    int i = c * 256 + tid, row = i >> 3, col = (i & 7) * 8;
    *(bf16x8*)&t[row][col] = *(const bf16x8*)&src[(size_t)(s0 + row) * 64 + col];
  }
  __syncthreads();
#pragma unroll
  for (int c = 0; c < 2; ++c) {
    int i = c * 256 + tid, dh = i >> 3, col = (i & 7) * 8;
    bf16x8 o;
#pragma unroll
    for (int j = 0; j < 8; ++j) o[j] = t[col + j][dh];
    *(bf16x8*)&dst[(size_t)dh * SEQ + s0 + col] = o;
  }
}

// ---------- flash attention with T5 bias (Q split hi/lo) ----------
__global__ __launch_bounds__(256) void k_attn(const __bf16* __restrict__ qhp,
                                              const __bf16* __restrict__ qlp,
                                              const __bf16* __restrict__ k,
                                              const __bf16* __restrict__ vt,
                                              const float* __restrict__ bias_tab,
                                              __bf16* __restrict__ ao) {
  __shared__ __align__(16) __bf16 Ks[2][64 * 64];
  __shared__ __align__(16) __bf16 Vs[2][64 * 64];
  __shared__ __align__(16) __bf16 Ps[4][16 * 64];  // per-wave P; also Q staging
  __shared__ float bias_s[2112];
  int tid = threadIdx.x, w = tid >> 6, l = tid & 63;
  int lr = l & 15, lh = l >> 4;
  int q0 = blockIdx.x * 64, bh = blockIdx.y, h = bh & 7, b = bh >> 3;
  const char* kbase = (const char*)(k + (size_t)bh * SEQ * 64);
  const char* vbase = (const char*)(vt + (size_t)bh * 64 * SEQ);

  for (int j = tid; j < 2112; j += 256)
    bias_s[j] = bias_tab[h * 4096 + (1984 - q0) + j];

  auto stageKV = [&](int kt, int buf) {
    const char* kb = kbase + (size_t)kt * 64 * 128;
    const char* vb = vbase + (size_t)kt * 128;
#pragma unroll
    for (int c = 0; c < 2; ++c) {
      int i = c * 256 + w * 64 + l;
      int row = i >> 3, colb = (i & 7) * 16;
      gl_lds16(kb + row * 128 + (colb ^ swz(row)), (char*)&Ks[buf][0] + (c * 256 + w * 64) * 16);
      gl_lds16(vb + (size_t)row * 4096 + (colb ^ swz(row)), (char*)&Vs[buf][0] + (c * 256 + w * 64) * 16);
    }
  };

  auto stageQ = [&](const __bf16* qsrc) {
    const char* qb = (const char*)(qsrc + (size_t)bh * SEQ * 64) + (size_t)q0 * 128;
#pragma unroll
    for (int c = 0; c < 2; ++c) {
      int i = c * 256 + w * 64 + l;
      int row = i >> 3, colb = (i & 7) * 16;
      gl_lds16(qb + row * 128 + (colb ^ swz(row)), (char*)&Ps[0][0] + (c * 256 + w * 64) * 16);
    }
  };

  bf16x8 qfh[2], qfl[2];
  int qrow = w * 16 + lr;
  const char* qread = (const char*)&Ps[0][0];

  stageQ(qhp);
  __syncthreads();
  qfh[0] = *(const bf16x8*)(qread + qrow * 128 + ((lh * 16) ^ swz(qrow)));
  qfh[1] = *(const bf16x8*)(qread + qrow * 128 + ((64 + lh * 16) ^ swz(qrow)));
  __syncthreads();
  stageQ(qlp);
  stageKV(0, 0);
  __syncthreads();
  qfl[0] = *(const bf16x8*)(qread + qrow * 128 + ((lh * 16) ^ swz(qrow)));
  qfl[1] = *(const bf16x8*)(qread + qrow * 128 + ((64 + lh * 16) ^ swz(qrow)));

  float m_run[4] = {-1e30f, -1e30f, -1e30f, -1e30f};
  float l_run[4] = {0.f, 0.f, 0.f, 0.f};
  f32x4 zero4 = {0.f, 0.f, 0.f, 0.f};
  f32x4 oacc[4];
#pragma unroll
  for (int i = 0; i < 4; ++i) oacc[i] = zero4;

  int cur = 0;
  for (int kt = 0; kt < 32; ++kt) {
    if (kt + 1 < 32) stageKV(kt + 1, cur ^ 1);
    const char* kb = (const char*)&Ks[cur][0];
    f32x4 sacc[4];
#pragma unroll
    for (int t = 0; t < 4; ++t) {
      int row = t * 16 + lr;
      bf16x8 b0 = *(const bf16x8*)(kb + row * 128 + ((lh * 16) ^ swz(row)));
      bf16x8 b1 = *(const bf16x8*)(kb + row * 128 + ((64 + lh * 16) ^ swz(row)));
      f32x4 z = zero4;
      z = __builtin_amdgcn_mfma_f32_16x16x32_bf16(qfh[0], b0, z, 0, 0, 0);
      z = __builtin_amdgcn_mfma_f32_16x16x32_bf16(qfh[1], b1, z, 0, 0, 0);
      z = __builtin_amdgcn_mfma_f32_16x16x32_bf16(qfl[0], b0, z, 0, 0, 0);
      z = __builtin_amdgcn_mfma_f32_16x16x32_bf16(qfl[1], b1, z, 0, 0, 0);
      sacc[t] = z;
    }
    float p[4][4];
    int jbase = kt * 64 + lr + 63 - (w * 16 + lh * 4);
#pragma unroll
    for (int r = 0; r < 4; ++r) {
      float mx = -1e30f;
#pragma unroll
      for (int t = 0; t < 4; ++t) {
        float sv = sacc[t][r] + bias_s[jbase + t * 16 - r];
        p[t][r] = sv;
        mx = fmaxf(mx, sv);
      }
      mx = fmaxf(mx, __shfl_xor(mx, 1));
      mx = fmaxf(mx, __shfl_xor(mx, 2));
      mx = fmaxf(mx, __shfl_xor(mx, 4));
      mx = fmaxf(mx, __shfl_xor(mx, 8));
      float mnew = fmaxf(m_run[r], mx);
      float sc = __expf(m_run[r] - mnew);
      m_run[r] = mnew;
      float rs = 0.f;
#pragma unroll
      for (int t = 0; t < 4; ++t) {
        float pv = __expf(p[t][r] - mnew);
        p[t][r] = pv;
        rs += pv;
      }
      rs += __shfl_xor(rs, 1);
      rs += __shfl_xor(rs, 2);
      rs += __shfl_xor(rs, 4);
      rs += __shfl_xor(rs, 8);
      l_run[r] = l_run[r] * sc + rs;
#pragma unroll
      for (int ni = 0; ni < 4; ++ni) oacc[ni][r] *= sc;
    }
    // P -> per-wave LDS (bf16, swizzled)
    char* pb = (char*)&Ps[w][0];
#pragma unroll
    for (int t = 0; t < 4; ++t)
#pragma unroll
      for (int r = 0; r < 4; ++r) {
        int row = lh * 4 + r;
        *(__bf16*)(pb + row * 128 + (((t * 16 + lr) * 2) ^ swz(row))) = (__bf16)p[t][r];
      }
    // PV
    {
      const char* pbr = (const char*)&Ps[w][0];
      const char* vbr = (const char*)&Vs[cur][0];
      bf16x8 pa0 = *(const bf16x8*)(pbr + lr * 128 + ((lh * 16) ^ swz(lr)));
      bf16x8 pa1 = *(const bf16x8*)(pbr + lr * 128 + ((64 + lh * 16) ^ swz(lr)));
#pragma unroll
      for (int ni = 0; ni < 4; ++ni) {
        int vrow = ni * 16 + lr;
        bf16x8 v0 = *(const bf16x8*)(vbr + vrow * 128 + ((lh * 16) ^ swz(vrow)));
        bf16x8 v1 = *(const bf16x8*)(vbr + vrow * 128 + ((64 + lh * 16) ^ swz(vrow)));
        oacc[ni] = __builtin_amdgcn_mfma_f32_16x16x32_bf16(pa0, v0, oacc[ni], 0, 0, 0);
        oacc[ni] = __builtin_amdgcn_mfma_f32_16x16x32_bf16(pa1, v1, oacc[ni], 0, 0, 0);
      }
    }
    __syncthreads();
    cur ^= 1;
  }

#pragma unroll
  for (int r = 0; r < 4; ++r) {
    float inv = 1.0f / l_run[r];
    int s = q0 + w * 16 + lh * 4 + r;
#pragma unroll
    for (int ni = 0; ni < 4; ++ni) {
      int dh = ni * 16 + lr;
      ao[((size_t)(b * 2048 + s)) * 512 + h * 64 + dh] = (__bf16)(oacc[ni][r] * inv);
    }
  }
}

extern "C" void kernel_launch(void* const* d_in, const int* in_sizes, int n_in,
                              void* d_out, int out_size, void* d_ws, size_t ws_size,
                              hipStream_t stream) {
  (void)in_sizes; (void)n_in; (void)out_size; (void)ws_size;
  const float* hs = (const float*)d_in[0];
  const float* Wq = (const float*)d_in[1];
  const float* Wk = (const float*)d_in[2];
  const float* Wv = (const float*)d_in[3];
  const float* Wo = (const float*)d_in[4];
  const float* rb = (const float*)d_in[5];
  char* ws = (char*)d_ws;
  __bf16* hs2    = (__bf16*)(ws + OFF_HS2);
  __bf16* wqkv2  = (__bf16*)(ws + OFF_WQKV2);
  __bf16* wo_t   = (__bf16*)(ws + OFF_WO);
  __bf16* qhb    = (__bf16*)(ws + OFF_QH);
  __bf16* qlb    = (__bf16*)(ws + OFF_QL);
  __bf16* kb     = (__bf16*)(ws + OFF_K);
  __bf16* vb     = (__bf16*)(ws + OFF_V);
  __bf16* vtb    = (__bf16*)(ws + OFF_VT);
  __bf16* aob    = (__bf16*)(ws + OFF_AO);
  float*  bias   = (float*)(ws + OFF_BIAS);

  k_cast_hs2<<<4096, 256, 0, stream>>>(hs, hs2);
  k_prep_w2<<<9216, 256, 0, stream>>>(Wq, Wk, Wv, wqkv2);
  k_prep_wo<<<1024, 256, 0, stream>>>(Wo, wo_t);
  k_bias<<<128, 256, 0, stream>>>(rb, bias);
  k_gemm<0, 48, 1024, 1536><<<dim3(12, 64), 256, 0, stream>>>(hs2, wqkv2, qhb, qlb, kb, vb, nullptr);
  k_transv<<<dim3(32, 32), 256, 0, stream>>>(vb, vtb);
  k_attn<<<dim3(32, 32), 256, 0, stream>>>(qhb, qlb, kb, vtb, bias, aob);
  k_gemm<1, 16, 512, 512><<<dim3(4, 64), 256, 0, stream>>>(aob, wo_t, nullptr, nullptr, nullptr, nullptr, (float*)d_out);
}

// Round 4
// 213.115 us; speedup vs baseline: 1.1786x; 1.1786x over previous
//
#include <hip/hip_runtime.h>
#include <stdint.h>

typedef __attribute__((ext_vector_type(8))) __bf16 bf16x8;
typedef __attribute__((ext_vector_type(4))) float f32x4;

#define SEQ 2048

// ---------- ws layout (bytes) ----------
// HS2 region [0, 16MB) is dead after the QKV GEMM; VT and AO overlay it.
#define OFF_HS2   0ull               // bf16 [8192][1024]  ([hi|lo] along K)
#define OFF_VT    0ull               // bf16 [32][64][2048]   (overlay, after GEMM)
#define OFF_AO    8388608ull         // bf16 [8192][512]      (overlay, after GEMM)
#define OFF_WQKV2 16777216ull        // bf16 [1536][1536]  (w_t[n][k'], k'=[hi|hi|lo])
#define OFF_WO    21495808ull        // bf16 [512][512]
#define OFF_QH    22020096ull        // bf16 [32][2048][64]
#define OFF_QL    30408704ull
#define OFF_K     38797312ull
#define OFF_V     47185920ull
#define OFF_BIAS  55574528ull        // f32 [8][4096]
// total 55,705,600 bytes (~53.1 MB)

__device__ __forceinline__ int swz(int row) { return ((row & 7) << 4) ^ ((row & 8) << 1); }

__device__ __forceinline__ void gl_lds16(const void* g, void* l) {
  __builtin_amdgcn_global_load_lds(
      (__attribute__((address_space(1))) void*)(uintptr_t)g,
      (__attribute__((address_space(3))) void*)(uint32_t)(uintptr_t)l, 16, 0, 0);
}

// ---------- prep: hidden_states f32 -> [hi|lo] bf16, K' = 1024 ----------
__global__ void k_cast_hs2(const float* __restrict__ hs, __bf16* __restrict__ out) {
  int gid = blockIdx.x * 256 + threadIdx.x;       // 8192*1024/8 threads
  int row = gid >> 7, c8 = (gid & 127) * 8;
  int src = (c8 < 512) ? c8 : c8 - 512;
  const float* p = hs + (size_t)row * 512 + src;
  float4 a = *(const float4*)p, b = *(const float4*)(p + 4);
  float v[8] = {a.x, a.y, a.z, a.w, b.x, b.y, b.z, b.w};
  bf16x8 o;
  if (c8 < 512) {
#pragma unroll
    for (int j = 0; j < 8; ++j) o[j] = (__bf16)v[j];
  } else {
#pragma unroll
    for (int j = 0; j < 8; ++j) { __bf16 h = (__bf16)v[j]; o[j] = (__bf16)(v[j] - (float)h); }
  }
  *(bf16x8*)(out + (size_t)row * 1024 + c8) = o;
}

// ---------- prep: QKV weights -> transposed split [1536][1536] ----------
__global__ void k_prep_w2(const float* __restrict__ Wq, const float* __restrict__ Wk,
                          const float* __restrict__ Wv, __bf16* __restrict__ w2) {
  int idx = blockIdx.x * 256 + threadIdx.x;       // 1536*1536
  int n = idx / 1536, kp = idx - n * 1536;
  const float* W = (n < 512) ? Wq : (n < 1024) ? Wk : Wv;
  int nn = n & 511;
  int k = (kp < 512) ? kp : (kp < 1024) ? kp - 512 : kp - 1024;
  float w = W[(size_t)k * 512 + nn];
  __bf16 h = (__bf16)w;
  w2[idx] = (kp < 1024) ? h : (__bf16)(w - (float)h);
}

__global__ void k_prep_wo(const float* __restrict__ Wo, __bf16* __restrict__ wo_t) {
  int idx = blockIdx.x * 256 + threadIdx.x;       // 512*512
  int n = idx >> 9, k = idx & 511;
  wo_t[idx] = (__bf16)Wo[(size_t)k * 512 + n];
}

// ---------- prep: T5 relative-position bias table ----------
// bucket thresholds derived from exact math of 8+int(log(rp/8)/log(16)*8):
// v = #{12,16,23,32,46,64,91} <= rp  (agrees with f32 reference at rp=16/32/64)
__global__ void k_bias(const float* __restrict__ rel_bias, float* __restrict__ bias_tab) {
  int idx = blockIdx.x * 256 + threadIdx.x;       // 8*4096
  int h = idx >> 12, dIdx = idx & 4095;
  float v = 0.f;
  if (dIdx < 4095) {
    int d = dIdx - 2047;                          // d = k - q
    int rp = d < 0 ? -d : d;
    int bp;
    if (rp < 8) bp = rp;
    else bp = 8 + (rp >= 12) + (rp >= 16) + (rp >= 23) + (rp >= 32) + (rp >= 46) + (rp >= 64) + (rp >= 91);
    v = rel_bias[((d > 0 ? 16 : 0) + bp) * 8 + h];
  }
  bias_tab[idx] = v;
}

// ---------- GEMM: C[M][N] = A[M][K'] @ Bt[N][K']^T  (128x128 tile, 16x16x32 bf16) ----------
// MODE 0: QKV split-K' GEMM (KSTEPS=48; A physical K=1024, kt>=32 remaps to hi segment)
// MODE 1: output projection, f32 out (KSTEPS=16)
template <int MODE, int KSTEPS, int LDA, int LDB>
__global__ __launch_bounds__(256) void k_gemm(const __bf16* __restrict__ A,
                                              const __bf16* __restrict__ Bt,
                                              __bf16* __restrict__ qh, __bf16* __restrict__ ql,
                                              __bf16* __restrict__ ko, __bf16* __restrict__ vo,
                                              float* __restrict__ fo) {
  __shared__ __align__(16) __bf16 As[2][128 * 32];
  __shared__ __align__(16) __bf16 Bs[2][128 * 32];
  int tid = threadIdx.x, w = tid >> 6, l = tid & 63;
  int lr = l & 15, lh = l >> 4;
  int m0 = blockIdx.y * 128, n0 = blockIdx.x * 128;
  int wm = (w >> 1) * 64, wn = (w & 1) * 64;
  f32x4 zero4 = {0.f, 0.f, 0.f, 0.f};
  f32x4 acc[4][4];
#pragma unroll
  for (int i = 0; i < 4; ++i)
#pragma unroll
    for (int j = 0; j < 4; ++j) acc[i][j] = zero4;

  auto stage = [&](int kt, int buf) {
    int ka = (MODE == 0 && kt >= 32) ? kt - 32 : kt;
#pragma unroll
    for (int c = 0; c < 2; ++c) {
      int i = c * 256 + w * 64 + l;
      int row = i >> 2, cc = i & 3;
      gl_lds16(A + (size_t)(m0 + row) * LDA + ka * 32 + cc * 8,
               (char*)&As[buf][0] + (c * 256 + w * 64) * 16);
      gl_lds16(Bt + (size_t)(n0 + row) * LDB + kt * 32 + cc * 8,
               (char*)&Bs[buf][0] + (c * 256 + w * 64) * 16);
    }
  };

  stage(0, 0);
  __syncthreads();
  int cur = 0;
  for (int kt = 0; kt < KSTEPS; ++kt) {
    if (kt + 1 < KSTEPS) stage(kt + 1, cur ^ 1);
    bf16x8 af[4], bfr[4];
#pragma unroll
    for (int mi = 0; mi < 4; ++mi)
      af[mi] = *(const bf16x8*)&As[cur][(wm + mi * 16 + lr) * 32 + lh * 8];
#pragma unroll
    for (int ni = 0; ni < 4; ++ni)
      bfr[ni] = *(const bf16x8*)&Bs[cur][(wn + ni * 16 + lr) * 32 + lh * 8];
#pragma unroll
    for (int mi = 0; mi < 4; ++mi)
#pragma unroll
      for (int ni = 0; ni < 4; ++ni)
        acc[mi][ni] = __builtin_amdgcn_mfma_f32_16x16x32_bf16(af[mi], bfr[ni], acc[mi][ni], 0, 0, 0);
    __syncthreads();
    cur ^= 1;
  }

#pragma unroll
  for (int mi = 0; mi < 4; ++mi)
#pragma unroll
    for (int ni = 0; ni < 4; ++ni)
#pragma unroll
      for (int r = 0; r < 4; ++r) {
        int m = m0 + wm + mi * 16 + lh * 4 + r;
        int n = n0 + wn + ni * 16 + lr;
        float vv = acc[mi][ni][r];
        if (MODE == 0) {
          int which = n >> 9, c9 = n & 511, hh = c9 >> 6, dh = c9 & 63;
          int b = m >> 11, s = m & 2047;
          size_t o = (size_t)((b * 8 + hh) * 2048 + s) * 64 + dh;
          if (which == 0) {
            __bf16 hv = (__bf16)vv;
            qh[o] = hv;
            ql[o] = (__bf16)(vv - (float)hv);
          } else if (which == 1) {
            ko[o] = (__bf16)vv;
          } else {
            vo[o] = (__bf16)vv;
          }
        } else {
          fo[(size_t)m * 512 + n] = vv;
        }
      }
}

// ---------- transpose V to [bh][dh][s] ----------
__global__ void k_transv(const __bf16* __restrict__ v, __bf16* __restrict__ vt) {
  __shared__ __bf16 t[64][72];
  int bh = blockIdx.y, s0 = blockIdx.x * 64, tid = threadIdx.x;
  const __bf16* src = v + (size_t)bh * SEQ * 64;
  __bf16* dst = vt + (size_t)bh * 64 * SEQ;
#pragma unroll
  for (int c = 0; c < 2; ++c) {
    int i = c * 256 + tid, row = i >> 3, col = (i & 7) * 8;
    *(bf16x8*)&t[row][col] = *(const bf16x8*)&src[(size_t)(s0 + row) * 64 + col];
  }
  __syncthreads();
#pragma unroll
  for (int c = 0; c < 2; ++c) {
    int i = c * 256 + tid, dh = i >> 3, col = (i & 7) * 8;
    bf16x8 o;
#pragma unroll
    for (int j = 0; j < 8; ++j) o[j] = t[col + j][dh];
    *(bf16x8*)&dst[(size_t)dh * SEQ + s0 + col] = o;
  }
}

// ---------- flash attention with T5 bias (Q split hi/lo), QBLK=128, 8 waves ----------
__global__ __launch_bounds__(512) void k_attn(const __bf16* __restrict__ qhp,
                                              const __bf16* __restrict__ qlp,
                                              const __bf16* __restrict__ k,
                                              const __bf16* __restrict__ vt,
                                              const float* __restrict__ bias_tab,
                                              __bf16* __restrict__ ao) {
  __shared__ __align__(16) __bf16 Ks[2][64 * 64];
  __shared__ __align__(16) __bf16 Vs[2][64 * 64];
  __shared__ __align__(16) __bf16 Ps[8][16 * 64];  // per-wave P; also 128x64 Q staging
  __shared__ float bias_s[2176];
  int tid = threadIdx.x, w = tid >> 6, l = tid & 63;
  int lr = l & 15, lh = l >> 4;
  // XCD-aware remap: all 16 q-tiles of a head land on one XCD (d%8 round-robin heuristic)
  int d = blockIdx.x;
  int bh = (d & 7) + ((d >> 3) & 3) * 8;
  int q0 = (d >> 5) * 128;
  int h = bh & 7, b = bh >> 3;
  const char* kbase = (const char*)(k + (size_t)bh * SEQ * 64);
  const char* vbase = (const char*)(vt + (size_t)bh * 64 * SEQ);

  for (int j = tid; j < 2176; j += 512)
    bias_s[j] = bias_tab[h * 4096 + (1920 - q0) + j];

  auto stageKV = [&](int kt, int buf) {
    const char* kb = kbase + (size_t)kt * 64 * 128;
    const char* vb = vbase + (size_t)kt * 128;
    int row = tid >> 3, colb = (tid & 7) * 16;
    gl_lds16(kb + row * 128 + (colb ^ swz(row)), (char*)&Ks[buf][0] + tid * 16);
    gl_lds16(vb + (size_t)row * 4096 + (colb ^ swz(row)), (char*)&Vs[buf][0] + tid * 16);
  };

  auto stageQ = [&](const __bf16* qsrc) {  // 128 rows x 64 cols into Ps
    const char* qb = (const char*)(qsrc + (size_t)bh * SEQ * 64) + (size_t)q0 * 128;
#pragma unroll
    for (int c = 0; c < 2; ++c) {
      int i = c * 512 + tid;
      int row = i >> 3, colb = (i & 7) * 16;
      gl_lds16(qb + row * 128 + (colb ^ swz(row)), (char*)&Ps[0][0] + i * 16);
    }
  };

  bf16x8 qfh[2], qfl[2];
  int qrow = w * 16 + lr;
  const char* qread = (const char*)&Ps[0][0];

  stageQ(qhp);
  __syncthreads();
  qfh[0] = *(const bf16x8*)(qread + qrow * 128 + ((lh * 16) ^ swz(qrow)));
  qfh[1] = *(const bf16x8*)(qread + qrow * 128 + ((64 + lh * 16) ^ swz(qrow)));
  __syncthreads();
  stageQ(qlp);
  stageKV(0, 0);
  __syncthreads();
  qfl[0] = *(const bf16x8*)(qread + qrow * 128 + ((lh * 16) ^ swz(qrow)));
  qfl[1] = *(const bf16x8*)(qread + qrow * 128 + ((64 + lh * 16) ^ swz(qrow)));

  float m_run[4] = {-1e30f, -1e30f, -1e30f, -1e30f};
  float l_run[4] = {0.f, 0.f, 0.f, 0.f};
  f32x4 zero4 = {0.f, 0.f, 0.f, 0.f};
  f32x4 oacc[4];
#pragma unroll
  for (int i = 0; i < 4; ++i) oacc[i] = zero4;

  int cur = 0;
  for (int kt = 0; kt < 32; ++kt) {
    if (kt + 1 < 32) stageKV(kt + 1, cur ^ 1);
    const char* kb = (const char*)&Ks[cur][0];
    f32x4 sacc[4];
#pragma unroll
    for (int t = 0; t < 4; ++t) {
      int row = t * 16 + lr;
      bf16x8 b0 = *(const bf16x8*)(kb + row * 128 + ((lh * 16) ^ swz(row)));
      bf16x8 b1 = *(const bf16x8*)(kb + row * 128 + ((64 + lh * 16) ^ swz(row)));
      f32x4 z = zero4;
      z = __builtin_amdgcn_mfma_f32_16x16x32_bf16(qfh[0], b0, z, 0, 0, 0);
      z = __builtin_amdgcn_mfma_f32_16x16x32_bf16(qfh[1], b1, z, 0, 0, 0);
      z = __builtin_amdgcn_mfma_f32_16x16x32_bf16(qfl[0], b0, z, 0, 0, 0);
      z = __builtin_amdgcn_mfma_f32_16x16x32_bf16(qfl[1], b1, z, 0, 0, 0);
      sacc[t] = z;
    }
    float p[4][4];
    int jbase = kt * 64 + lr + 127 - (w * 16 + lh * 4);
#pragma unroll
    for (int r = 0; r < 4; ++r) {
      float mx = -1e30f;
#pragma unroll
      for (int t = 0; t < 4; ++t) {
        float sv = sacc[t][r] + bias_s[jbase + t * 16 - r];
        p[t][r] = sv;
        mx = fmaxf(mx, sv);
      }
      mx = fmaxf(mx, __shfl_xor(mx, 1));
      mx = fmaxf(mx, __shfl_xor(mx, 2));
      mx = fmaxf(mx, __shfl_xor(mx, 4));
      mx = fmaxf(mx, __shfl_xor(mx, 8));
      float mnew = fmaxf(m_run[r], mx);
      float sc = __expf(m_run[r] - mnew);
      m_run[r] = mnew;
      float rs = 0.f;
#pragma unroll
      for (int t = 0; t < 4; ++t) {
        float pv = __expf(p[t][r] - mnew);
        p[t][r] = pv;
        rs += pv;
      }
      rs += __shfl_xor(rs, 1);
      rs += __shfl_xor(rs, 2);
      rs += __shfl_xor(rs, 4);
      rs += __shfl_xor(rs, 8);
      l_run[r] = l_run[r] * sc + rs;
#pragma unroll
      for (int ni = 0; ni < 4; ++ni) oacc[ni][r] *= sc;
    }
    // P -> per-wave LDS (bf16, swizzled)
    char* pb = (char*)&Ps[w][0];
#pragma unroll
    for (int t = 0; t < 4; ++t)
#pragma unroll
      for (int r = 0; r < 4; ++r) {
        int row = lh * 4 + r;
        *(__bf16*)(pb + row * 128 + (((t * 16 + lr) * 2) ^ swz(row))) = (__bf16)p[t][r];
      }
    // PV
    {
      const char* pbr = (const char*)&Ps[w][0];
      const char* vbr = (const char*)&Vs[cur][0];
      bf16x8 pa0 = *(const bf16x8*)(pbr + lr * 128 + ((lh * 16) ^ swz(lr)));
      bf16x8 pa1 = *(const bf16x8*)(pbr + lr * 128 + ((64 + lh * 16) ^ swz(lr)));
#pragma unroll
      for (int ni = 0; ni < 4; ++ni) {
        int vrow = ni * 16 + lr;
        bf16x8 v0 = *(const bf16x8*)(vbr + vrow * 128 + ((lh * 16) ^ swz(vrow)));
        bf16x8 v1 = *(const bf16x8*)(vbr + vrow * 128 + ((64 + lh * 16) ^ swz(vrow)));
        oacc[ni] = __builtin_amdgcn_mfma_f32_16x16x32_bf16(pa0, v0, oacc[ni], 0, 0, 0);
        oacc[ni] = __builtin_amdgcn_mfma_f32_16x16x32_bf16(pa1, v1, oacc[ni], 0, 0, 0);
      }
    }
    __syncthreads();
    cur ^= 1;
  }

#pragma unroll
  for (int r = 0; r < 4; ++r) {
    float inv = 1.0f / l_run[r];
    int s = q0 + w * 16 + lh * 4 + r;
#pragma unroll
    for (int ni = 0; ni < 4; ++ni) {
      int dh = ni * 16 + lr;
      ao[((size_t)(b * 2048 + s)) * 512 + h * 64 + dh] = (__bf16)(oacc[ni][r] * inv);
    }
  }
}

extern "C" void kernel_launch(void* const* d_in, const int* in_sizes, int n_in,
                              void* d_out, int out_size, void* d_ws, size_t ws_size,
                              hipStream_t stream) {
  (void)in_sizes; (void)n_in; (void)out_size; (void)ws_size;
  const float* hs = (const float*)d_in[0];
  const float* Wq = (const float*)d_in[1];
  const float* Wk = (const float*)d_in[2];
  const float* Wv = (const float*)d_in[3];
  const float* Wo = (const float*)d_in[4];
  const float* rb = (const float*)d_in[5];
  char* ws = (char*)d_ws;
  __bf16* hs2    = (__bf16*)(ws + OFF_HS2);
  __bf16* wqkv2  = (__bf16*)(ws + OFF_WQKV2);
  __bf16* wo_t   = (__bf16*)(ws + OFF_WO);
  __bf16* qhb    = (__bf16*)(ws + OFF_QH);
  __bf16* qlb    = (__bf16*)(ws + OFF_QL);
  __bf16* kb     = (__bf16*)(ws + OFF_K);
  __bf16* vb     = (__bf16*)(ws + OFF_V);
  __bf16* vtb    = (__bf16*)(ws + OFF_VT);
  __bf16* aob    = (__bf16*)(ws + OFF_AO);
  float*  bias   = (float*)(ws + OFF_BIAS);

  k_cast_hs2<<<4096, 256, 0, stream>>>(hs, hs2);
  k_prep_w2<<<9216, 256, 0, stream>>>(Wq, Wk, Wv, wqkv2);
  k_prep_wo<<<1024, 256, 0, stream>>>(Wo, wo_t);
  k_bias<<<128, 256, 0, stream>>>(rb, bias);
  k_gemm<0, 48, 1024, 1536><<<dim3(12, 64), 256, 0, stream>>>(hs2, wqkv2, qhb, qlb, kb, vb, nullptr);
  k_transv<<<dim3(32, 32), 256, 0, stream>>>(vb, vtb);
  k_attn<<<dim3(512), 512, 0, stream>>>(qhb, qlb, kb, vtb, bias, aob);
  k_gemm<1, 16, 512, 512><<<dim3(4, 64), 256, 0, stream>>>(aob, wo_t, nullptr, nullptr, nullptr, nullptr, (float*)d_out);
}

// Round 5
// 176.767 us; speedup vs baseline: 1.4210x; 1.2056x over previous
//
#include <hip/hip_runtime.h>
#include <stdint.h>

typedef __attribute__((ext_vector_type(8))) __bf16 bf16x8;
typedef __attribute__((ext_vector_type(4))) float f32x4;

#define SEQ 2048

// ---------- ws layout (bytes) ----------
#define OFF_HS2   0ull               // bf16 [8192][1024]  ([hi|lo] along K)
#define OFF_VT    0ull               // bf16 [32][64][2048]   (overlay, after GEMM)
#define OFF_AO    8388608ull         // bf16 [8192][512]      (overlay, after GEMM)
#define OFF_WQKV2 16777216ull        // bf16 [1536][1536]  (w_t[n][k'], k'=[hi|hi|lo])
#define OFF_WO    21495808ull        // bf16 [512][512]
#define OFF_QH    22020096ull        // bf16 [32][2048][64]
#define OFF_QL    30408704ull
#define OFF_K     38797312ull
#define OFF_V     47185920ull
#define OFF_BIAS  55574528ull        // f32 [8][4096]

__device__ __forceinline__ int swz(int row) { return ((row & 7) << 4) ^ ((row & 8) << 1); }

__device__ __forceinline__ void gl_lds16(const void* g, void* l) {
  __builtin_amdgcn_global_load_lds(
      (__attribute__((address_space(1))) void*)(uintptr_t)g,
      (__attribute__((address_space(3))) void*)(uint32_t)(uintptr_t)l, 16, 0, 0);
}

// ---------- prep: hidden_states f32 -> [hi|lo] bf16, K' = 1024 ----------
__global__ void k_cast_hs2(const float* __restrict__ hs, __bf16* __restrict__ out) {
  int gid = blockIdx.x * 256 + threadIdx.x;
  int row = gid >> 7, c8 = (gid & 127) * 8;
  int src = (c8 < 512) ? c8 : c8 - 512;
  const float* p = hs + (size_t)row * 512 + src;
  float4 a = *(const float4*)p, b = *(const float4*)(p + 4);
  float v[8] = {a.x, a.y, a.z, a.w, b.x, b.y, b.z, b.w};
  bf16x8 o;
  if (c8 < 512) {
#pragma unroll
    for (int j = 0; j < 8; ++j) o[j] = (__bf16)v[j];
  } else {
#pragma unroll
    for (int j = 0; j < 8; ++j) { __bf16 h = (__bf16)v[j]; o[j] = (__bf16)(v[j] - (float)h); }
  }
  *(bf16x8*)(out + (size_t)row * 1024 + c8) = o;
}

// ---------- prep: QKV weights -> transposed split [1536][1536] ----------
__global__ void k_prep_w2(const float* __restrict__ Wq, const float* __restrict__ Wk,
                          const float* __restrict__ Wv, __bf16* __restrict__ w2) {
  int idx = blockIdx.x * 256 + threadIdx.x;
  int n = idx / 1536, kp = idx - n * 1536;
  const float* W = (n < 512) ? Wq : (n < 1024) ? Wk : Wv;
  int nn = n & 511;
  int k = (kp < 512) ? kp : (kp < 1024) ? kp - 512 : kp - 1024;
  float w = W[(size_t)k * 512 + nn];
  __bf16 h = (__bf16)w;
  w2[idx] = (kp < 1024) ? h : (__bf16)(w - (float)h);
}

__global__ void k_prep_wo(const float* __restrict__ Wo, __bf16* __restrict__ wo_t) {
  int idx = blockIdx.x * 256 + threadIdx.x;
  int n = idx >> 9, k = idx & 511;
  wo_t[idx] = (__bf16)Wo[(size_t)k * 512 + n];
}

// ---------- prep: T5 relative-position bias table ----------
__global__ void k_bias(const float* __restrict__ rel_bias, float* __restrict__ bias_tab) {
  int idx = blockIdx.x * 256 + threadIdx.x;
  int h = idx >> 12, dIdx = idx & 4095;
  float v = 0.f;
  if (dIdx < 4095) {
    int d = dIdx - 2047;
    int rp = d < 0 ? -d : d;
    int bp;
    if (rp < 8) bp = rp;
    else bp = 8 + (rp >= 12) + (rp >= 16) + (rp >= 23) + (rp >= 32) + (rp >= 46) + (rp >= 64) + (rp >= 91);
    v = rel_bias[((d > 0 ? 16 : 0) + bp) * 8 + h];
  }
  bias_tab[idx] = v;
}

// ---------- GEMM (unchanged) ----------
template <int MODE, int KSTEPS, int LDA, int LDB>
__global__ __launch_bounds__(256) void k_gemm(const __bf16* __restrict__ A,
                                              const __bf16* __restrict__ Bt,
                                              __bf16* __restrict__ qh, __bf16* __restrict__ ql,
                                              __bf16* __restrict__ ko, __bf16* __restrict__ vo,
                                              float* __restrict__ fo) {
  __shared__ __align__(16) __bf16 As[2][128 * 32];
  __shared__ __align__(16) __bf16 Bs[2][128 * 32];
  int tid = threadIdx.x, w = tid >> 6, l = tid & 63;
  int lr = l & 15, lh = l >> 4;
  int m0 = blockIdx.y * 128, n0 = blockIdx.x * 128;
  int wm = (w >> 1) * 64, wn = (w & 1) * 64;
  f32x4 zero4 = {0.f, 0.f, 0.f, 0.f};
  f32x4 acc[4][4];
#pragma unroll
  for (int i = 0; i < 4; ++i)
#pragma unroll
    for (int j = 0; j < 4; ++j) acc[i][j] = zero4;

  auto stage = [&](int kt, int buf) {
    int ka = (MODE == 0 && kt >= 32) ? kt - 32 : kt;
#pragma unroll
    for (int c = 0; c < 2; ++c) {
      int i = c * 256 + w * 64 + l;
      int row = i >> 2, cc = i & 3;
      gl_lds16(A + (size_t)(m0 + row) * LDA + ka * 32 + cc * 8,
               (char*)&As[buf][0] + (c * 256 + w * 64) * 16);
      gl_lds16(Bt + (size_t)(n0 + row) * LDB + kt * 32 + cc * 8,
               (char*)&Bs[buf][0] + (c * 256 + w * 64) * 16);
    }
  };

  stage(0, 0);
  __syncthreads();
  int cur = 0;
  for (int kt = 0; kt < KSTEPS; ++kt) {
    if (kt + 1 < KSTEPS) stage(kt + 1, cur ^ 1);
    bf16x8 af[4], bfr[4];
#pragma unroll
    for (int mi = 0; mi < 4; ++mi)
      af[mi] = *(const bf16x8*)&As[cur][(wm + mi * 16 + lr) * 32 + lh * 8];
#pragma unroll
    for (int ni = 0; ni < 4; ++ni)
      bfr[ni] = *(const bf16x8*)&Bs[cur][(wn + ni * 16 + lr) * 32 + lh * 8];
#pragma unroll
    for (int mi = 0; mi < 4; ++mi)
#pragma unroll
      for (int ni = 0; ni < 4; ++ni)
        acc[mi][ni] = __builtin_amdgcn_mfma_f32_16x16x32_bf16(af[mi], bfr[ni], acc[mi][ni], 0, 0, 0);
    __syncthreads();
    cur ^= 1;
  }

#pragma unroll
  for (int mi = 0; mi < 4; ++mi)
#pragma unroll
    for (int ni = 0; ni < 4; ++ni)
#pragma unroll
      for (int r = 0; r < 4; ++r) {
        int m = m0 + wm + mi * 16 + lh * 4 + r;
        int n = n0 + wn + ni * 16 + lr;
        float vv = acc[mi][ni][r];
        if (MODE == 0) {
          int which = n >> 9, c9 = n & 511, hh = c9 >> 6, dh = c9 & 63;
          int b = m >> 11, s = m & 2047;
          size_t o = (size_t)((b * 8 + hh) * 2048 + s) * 64 + dh;
          if (which == 0) {
            __bf16 hv = (__bf16)vv;
            qh[o] = hv;
            ql[o] = (__bf16)(vv - (float)hv);
          } else if (which == 1) {
            ko[o] = (__bf16)vv;
          } else {
            vo[o] = (__bf16)vv;
          }
        } else {
          fo[(size_t)m * 512 + n] = vv;
        }
      }
}

// ---------- transpose V to [bh][dh][s] ----------
__global__ void k_transv(const __bf16* __restrict__ v, __bf16* __restrict__ vt) {
  __shared__ __bf16 t[64][72];
  int bh = blockIdx.y, s0 = blockIdx.x * 64, tid = threadIdx.x;
  const __bf16* src = v + (size_t)bh * SEQ * 64;
  __bf16* dst = vt + (size_t)bh * 64 * SEQ;
#pragma unroll
  for (int c = 0; c < 2; ++c) {
    int i = c * 256 + tid, row = i >> 3, col = (i & 7) * 8;
    *(bf16x8*)&t[row][col] = *(const bf16x8*)&src[(size_t)(s0 + row) * 64 + col];
  }
  __syncthreads();
#pragma unroll
  for (int c = 0; c < 2; ++c) {
    int i = c * 256 + tid, dh = i >> 3, col = (i & 7) * 8;
    bf16x8 o;
#pragma unroll
    for (int j = 0; j < 8; ++j) o[j] = t[col + j][dh];
    *(bf16x8*)&dst[(size_t)dh * SEQ + s0 + col] = o;
  }
}

// ---------- flash attention, swapped QK^T (lane-local q rows) ----------
__global__ __launch_bounds__(512) void k_attn(const __bf16* __restrict__ qhp,
                                              const __bf16* __restrict__ qlp,
                                              const __bf16* __restrict__ k,
                                              const __bf16* __restrict__ vt,
                                              const float* __restrict__ bias_tab,
                                              __bf16* __restrict__ ao) {
  __shared__ __align__(16) __bf16 Ks[2][64 * 64];
  __shared__ __align__(16) __bf16 Vs[2][64 * 64];
  __shared__ __align__(16) __bf16 Ps[8][16 * 64];  // per-wave P; also 128x64 Q staging
  __shared__ float bias_s[2176];
  int tid = threadIdx.x, w = tid >> 6, l = tid & 63;
  int lr = l & 15, lh = l >> 4;
  int d = blockIdx.x;
  int bh = (d & 7) + ((d >> 3) & 3) * 8;
  int q0 = (d >> 5) * 128;
  int h = bh & 7, b = bh >> 3;
  const char* kbase = (const char*)(k + (size_t)bh * SEQ * 64);
  const char* vbase = (const char*)(vt + (size_t)bh * 64 * SEQ);

  for (int j = tid; j < 2176; j += 512)
    bias_s[j] = bias_tab[h * 4096 + (1920 - q0) + j];

  auto stageKV = [&](int kt, int buf) {
    const char* kb = kbase + (size_t)kt * 64 * 128;
    const char* vb = vbase + (size_t)kt * 128;
    int row = tid >> 3, colb = (tid & 7) * 16;
    gl_lds16(kb + row * 128 + (colb ^ swz(row)), (char*)&Ks[buf][0] + tid * 16);
    gl_lds16(vb + (size_t)row * 4096 + (colb ^ swz(row)), (char*)&Vs[buf][0] + tid * 16);
  };

  auto stageQ = [&](const __bf16* qsrc) {
    const char* qb = (const char*)(qsrc + (size_t)bh * SEQ * 64) + (size_t)q0 * 128;
#pragma unroll
    for (int c = 0; c < 2; ++c) {
      int i = c * 512 + tid;
      int row = i >> 3, colb = (i & 7) * 16;
      gl_lds16(qb + row * 128 + (colb ^ swz(row)), (char*)&Ps[0][0] + i * 16);
    }
  };

  bf16x8 qfh[2], qfl[2];
  int qrow = w * 16 + lr;
  const char* qread = (const char*)&Ps[0][0];

  stageQ(qhp);
  __syncthreads();
  qfh[0] = *(const bf16x8*)(qread + qrow * 128 + ((lh * 16) ^ swz(qrow)));
  qfh[1] = *(const bf16x8*)(qread + qrow * 128 + ((64 + lh * 16) ^ swz(qrow)));
  __syncthreads();
  stageQ(qlp);
  stageKV(0, 0);
  __syncthreads();
  qfl[0] = *(const bf16x8*)(qread + qrow * 128 + ((lh * 16) ^ swz(qrow)));
  qfl[1] = *(const bf16x8*)(qread + qrow * 128 + ((64 + lh * 16) ^ swz(qrow)));

  float m_run = -1e30f, l_run = 0.f;
  f32x4 zero4 = {0.f, 0.f, 0.f, 0.f};
  f32x4 oacc[4];
#pragma unroll
  for (int i = 0; i < 4; ++i) oacc[i] = zero4;

#pragma unroll 2
  for (int kt = 0; kt < 32; ++kt) {
    int cur = kt & 1;
    if (kt + 1 < 32) stageKV(kt + 1, cur ^ 1);
    const char* kb = (const char*)&Ks[cur][0];
    f32x4 sacc[4];
    __builtin_amdgcn_s_setprio(1);
#pragma unroll
    for (int t = 0; t < 4; ++t) {
      int row = t * 16 + lr;
      bf16x8 b0 = *(const bf16x8*)(kb + row * 128 + ((lh * 16) ^ swz(row)));
      bf16x8 b1 = *(const bf16x8*)(kb + row * 128 + ((64 + lh * 16) ^ swz(row)));
      f32x4 z = zero4;
      z = __builtin_amdgcn_mfma_f32_16x16x32_bf16(b0, qfh[0], z, 0, 0, 0);
      z = __builtin_amdgcn_mfma_f32_16x16x32_bf16(b1, qfh[1], z, 0, 0, 0);
      z = __builtin_amdgcn_mfma_f32_16x16x32_bf16(b0, qfl[0], z, 0, 0, 0);
      z = __builtin_amdgcn_mfma_f32_16x16x32_bf16(b1, qfl[1], z, 0, 0, 0);
      sacc[t] = z;
    }
    __builtin_amdgcn_s_setprio(0);
    // lane (lr,lh) reg (t,r): S[q = q0+w*16+lr][k = kt*64 + t*16 + lh*4 + r]
    float p[4][4];
    int jb = kt * 64 + lh * 4 + 127 - (w * 16 + lr);
    float mx = -1e30f;
#pragma unroll
    for (int t = 0; t < 4; ++t)
#pragma unroll
      for (int r = 0; r < 4; ++r) {
        float sv = sacc[t][r] + bias_s[jb + t * 16 + r];
        p[t][r] = sv;
        mx = fmaxf(mx, sv);
      }
    mx = fmaxf(mx, __shfl_xor(mx, 16));
    mx = fmaxf(mx, __shfl_xor(mx, 32));
    float mnew = fmaxf(m_run, mx);
    float sc = __expf(m_run - mnew);
    m_run = mnew;
    float rs = 0.f;
#pragma unroll
    for (int t = 0; t < 4; ++t)
#pragma unroll
      for (int r = 0; r < 4; ++r) {
        float pv = __expf(p[t][r] - mnew);
        p[t][r] = pv;
        rs += pv;
      }
    rs += __shfl_xor(rs, 16);
    rs += __shfl_xor(rs, 32);
    l_run = l_run * sc + rs;
    // rescale oacc rows (output row q_local = lh*4+r; its sc lives at lane lr'=lh*4+r)
#pragma unroll
    for (int r = 0; r < 4; ++r) {
      float scr = __shfl(sc, lh * 4 + r);
#pragma unroll
      for (int ni = 0; ni < 4; ++ni) oacc[ni][r] *= scr;
    }
    // P -> per-wave LDS, packed b64 writes (row = lr, full 64-k row per 4 lanes)
    {
      char* pb = (char*)&Ps[w][0];
#pragma unroll
      for (int t = 0; t < 4; ++t) {
        uint32_t d0, d1;
        asm("v_cvt_pk_bf16_f32 %0, %1, %2" : "=v"(d0) : "v"(p[t][0]), "v"(p[t][1]));
        asm("v_cvt_pk_bf16_f32 %0, %1, %2" : "=v"(d1) : "v"(p[t][2]), "v"(p[t][3]));
        uint2 dd = {d0, d1};
        *(uint2*)(pb + lr * 128 + ((t * 32 + lh * 8) ^ swz(lr))) = dd;
      }
    }
    // PV
    {
      const char* pbr = (const char*)&Ps[w][0];
      const char* vbr = (const char*)&Vs[cur][0];
      bf16x8 pa0 = *(const bf16x8*)(pbr + lr * 128 + ((lh * 16) ^ swz(lr)));
      bf16x8 pa1 = *(const bf16x8*)(pbr + lr * 128 + ((64 + lh * 16) ^ swz(lr)));
      __builtin_amdgcn_s_setprio(1);
#pragma unroll
      for (int ni = 0; ni < 4; ++ni) {
        int vrow = ni * 16 + lr;
        bf16x8 v0 = *(const bf16x8*)(vbr + vrow * 128 + ((lh * 16) ^ swz(vrow)));
        bf16x8 v1 = *(const bf16x8*)(vbr + vrow * 128 + ((64 + lh * 16) ^ swz(vrow)));
        oacc[ni] = __builtin_amdgcn_mfma_f32_16x16x32_bf16(pa0, v0, oacc[ni], 0, 0, 0);
        oacc[ni] = __builtin_amdgcn_mfma_f32_16x16x32_bf16(pa1, v1, oacc[ni], 0, 0, 0);
      }
      __builtin_amdgcn_s_setprio(0);
    }
    __syncthreads();
  }

#pragma unroll
  for (int r = 0; r < 4; ++r) {
    float linv = 1.0f / __shfl(l_run, lh * 4 + r);
    int s = q0 + w * 16 + lh * 4 + r;
#pragma unroll
    for (int ni = 0; ni < 4; ++ni) {
      int dh = ni * 16 + lr;
      ao[((size_t)(b * 2048 + s)) * 512 + h * 64 + dh] = (__bf16)(oacc[ni][r] * linv);
    }
  }
}

extern "C" void kernel_launch(void* const* d_in, const int* in_sizes, int n_in,
                              void* d_out, int out_size, void* d_ws, size_t ws_size,
                              hipStream_t stream) {
  (void)in_sizes; (void)n_in; (void)out_size; (void)ws_size;
  const float* hs = (const float*)d_in[0];
  const float* Wq = (const float*)d_in[1];
  const float* Wk = (const float*)d_in[2];
  const float* Wv = (const float*)d_in[3];
  const float* Wo = (const float*)d_in[4];
  const float* rb = (const float*)d_in[5];
  char* ws = (char*)d_ws;
  __bf16* hs2    = (__bf16*)(ws + OFF_HS2);
  __bf16* wqkv2  = (__bf16*)(ws + OFF_WQKV2);
  __bf16* wo_t   = (__bf16*)(ws + OFF_WO);
  __bf16* qhb    = (__bf16*)(ws + OFF_QH);
  __bf16* qlb    = (__bf16*)(ws + OFF_QL);
  __bf16* kb     = (__bf16*)(ws + OFF_K);
  __bf16* vb     = (__bf16*)(ws + OFF_V);
  __bf16* vtb    = (__bf16*)(ws + OFF_VT);
  __bf16* aob    = (__bf16*)(ws + OFF_AO);
  float*  bias   = (float*)(ws + OFF_BIAS);

  k_cast_hs2<<<4096, 256, 0, stream>>>(hs, hs2);
  k_prep_w2<<<9216, 256, 0, stream>>>(Wq, Wk, Wv, wqkv2);
  k_prep_wo<<<1024, 256, 0, stream>>>(Wo, wo_t);
  k_bias<<<128, 256, 0, stream>>>(rb, bias);
  k_gemm<0, 48, 1024, 1536><<<dim3(12, 64), 256, 0, stream>>>(hs2, wqkv2, qhb, qlb, kb, vb, nullptr);
  k_transv<<<dim3(32, 32), 256, 0, stream>>>(vb, vtb);
  k_attn<<<dim3(512), 512, 0, stream>>>(qhb, qlb, kb, vtb, bias, aob);
  k_gemm<1, 16, 512, 512><<<dim3(4, 64), 256, 0, stream>>>(aob, wo_t, nullptr, nullptr, nullptr, nullptr, (float*)d_out);
}

// Round 7
// 164.117 us; speedup vs baseline: 1.5305x; 1.0771x over previous
//
#include <hip/hip_runtime.h>
#include <stdint.h>

typedef __attribute__((ext_vector_type(8))) __bf16 bf16x8;
typedef __attribute__((ext_vector_type(4))) __bf16 bf16x4;
typedef __attribute__((ext_vector_type(4))) float f32x4;
typedef __attribute__((ext_vector_type(4))) unsigned int u32x4;

#define SEQ 2048

// ---------- ws layout (bytes) ----------
#define OFF_HS2   0ull               // bf16 [8192][1024]  ([hi|lo] along K)
#define OFF_VT    0ull               // bf16 [32][64][2048]   (overlay, after GEMM; k-permuted cols)
#define OFF_AO    8388608ull         // bf16 [8192][512]      (overlay, after GEMM)
#define OFF_WQKV2 16777216ull        // bf16 [1536][1536]  (w_t[n][k'], k'=[hi|hi|lo])
#define OFF_WO    21495808ull        // bf16 [512][512]
#define OFF_QH    22020096ull        // bf16 [32][2048][64]
#define OFF_QL    30408704ull
#define OFF_K     38797312ull
#define OFF_V     47185920ull
#define OFF_BIAS  55574528ull        // f32 [8][4096]

__device__ __forceinline__ int swz(int row) { return ((row & 7) << 4) ^ ((row & 8) << 1); }

__device__ __forceinline__ void gl_lds16(const void* g, void* l) {
  __builtin_amdgcn_global_load_lds(
      (__attribute__((address_space(1))) void*)(uintptr_t)g,
      (__attribute__((address_space(3))) void*)(uint32_t)(uintptr_t)l, 16, 0, 0);
}

// ---------- prep: hidden_states f32 -> [hi|lo] bf16, K' = 1024 (read once) ----------
__global__ void k_cast_hs2(const float* __restrict__ hs, __bf16* __restrict__ out) {
  int gid = blockIdx.x * 256 + threadIdx.x;       // 524288
  int row = gid >> 6, c8 = (gid & 63) * 8;
  const float* p = hs + (size_t)row * 512 + c8;
  float4 a = *(const float4*)p, b = *(const float4*)(p + 4);
  float v[8] = {a.x, a.y, a.z, a.w, b.x, b.y, b.z, b.w};
  bf16x8 hi, lo;
#pragma unroll
  for (int j = 0; j < 8; ++j) {
    __bf16 h = (__bf16)v[j];
    hi[j] = h;
    lo[j] = (__bf16)(v[j] - (float)h);
  }
  *(bf16x8*)(out + (size_t)row * 1024 + c8) = hi;
  *(bf16x8*)(out + (size_t)row * 1024 + 512 + c8) = lo;
}

// ---------- prep: QKV weights -> transposed split [1536][1536], LDS-tiled ----------
__global__ void k_prep_w2(const float* __restrict__ Wq, const float* __restrict__ Wk,
                          const float* __restrict__ Wv, __bf16* __restrict__ w2) {
  __shared__ float tile[64][65];
  int z = blockIdx.z;
  const float* W = (z == 0) ? Wq : (z == 1) ? Wk : Wv;
  int k0 = blockIdx.y * 64, n0 = blockIdx.x * 64;
  int tx = threadIdx.x & 63, ty = threadIdx.x >> 6;
  for (int r = ty; r < 64; r += 4) tile[r][tx] = W[(size_t)(k0 + r) * 512 + n0 + tx];
  __syncthreads();
  for (int r = ty; r < 64; r += 4) {
    float v = tile[tx][r];                       // (k=k0+tx, n=n0+r)
    __bf16 h = (__bf16)v;
    __bf16 lo = (__bf16)(v - (float)h);
    __bf16* dst = w2 + (size_t)(z * 512 + n0 + r) * 1536;
    dst[k0 + tx] = h;
    dst[512 + k0 + tx] = h;
    dst[1024 + k0 + tx] = lo;
  }
}

__global__ void k_prep_wo(const float* __restrict__ Wo, __bf16* __restrict__ wo_t) {
  int idx = blockIdx.x * 256 + threadIdx.x;
  int n = idx >> 9, k = idx & 511;
  wo_t[idx] = (__bf16)Wo[(size_t)k * 512 + n];
}

// ---------- prep: T5 relative-position bias table ----------
__global__ void k_bias(const float* __restrict__ rel_bias, float* __restrict__ bias_tab) {
  int idx = blockIdx.x * 256 + threadIdx.x;
  int h = idx >> 12, dIdx = idx & 4095;
  float v = 0.f;
  if (dIdx < 4095) {
    int d = dIdx - 2047;
    int rp = d < 0 ? -d : d;
    int bp;
    if (rp < 8) bp = rp;
    else bp = 8 + (rp >= 12) + (rp >= 16) + (rp >= 23) + (rp >= 32) + (rp >= 46) + (rp >= 64) + (rp >= 91);
    v = rel_bias[((d > 0 ? 16 : 0) + bp) * 8 + h];
  }
  bias_tab[idx] = v;
}

// ---------- GEMM (unchanged) ----------
template <int MODE, int KSTEPS, int LDA, int LDB>
__global__ __launch_bounds__(256) void k_gemm(const __bf16* __restrict__ A,
                                              const __bf16* __restrict__ Bt,
                                              __bf16* __restrict__ qh, __bf16* __restrict__ ql,
                                              __bf16* __restrict__ ko, __bf16* __restrict__ vo,
                                              float* __restrict__ fo) {
  __shared__ __align__(16) __bf16 As[2][128 * 32];
  __shared__ __align__(16) __bf16 Bs[2][128 * 32];
  int tid = threadIdx.x, w = tid >> 6, l = tid & 63;
  int lr = l & 15, lh = l >> 4;
  int m0 = blockIdx.y * 128, n0 = blockIdx.x * 128;
  int wm = (w >> 1) * 64, wn = (w & 1) * 64;
  f32x4 zero4 = {0.f, 0.f, 0.f, 0.f};
  f32x4 acc[4][4];
#pragma unroll
  for (int i = 0; i < 4; ++i)
#pragma unroll
    for (int j = 0; j < 4; ++j) acc[i][j] = zero4;

  auto stage = [&](int kt, int buf) {
    int ka = (MODE == 0 && kt >= 32) ? kt - 32 : kt;
#pragma unroll
    for (int c = 0; c < 2; ++c) {
      int i = c * 256 + w * 64 + l;
      int row = i >> 2, cc = i & 3;
      gl_lds16(A + (size_t)(m0 + row) * LDA + ka * 32 + cc * 8,
               (char*)&As[buf][0] + (c * 256 + w * 64) * 16);
      gl_lds16(Bt + (size_t)(n0 + row) * LDB + kt * 32 + cc * 8,
               (char*)&Bs[buf][0] + (c * 256 + w * 64) * 16);
    }
  };

  stage(0, 0);
  __syncthreads();
  int cur = 0;
  for (int kt = 0; kt < KSTEPS; ++kt) {
    if (kt + 1 < KSTEPS) stage(kt + 1, cur ^ 1);
    bf16x8 af[4], bfr[4];
#pragma unroll
    for (int mi = 0; mi < 4; ++mi)
      af[mi] = *(const bf16x8*)&As[cur][(wm + mi * 16 + lr) * 32 + lh * 8];
#pragma unroll
    for (int ni = 0; ni < 4; ++ni)
      bfr[ni] = *(const bf16x8*)&Bs[cur][(wn + ni * 16 + lr) * 32 + lh * 8];
#pragma unroll
    for (int mi = 0; mi < 4; ++mi)
#pragma unroll
      for (int ni = 0; ni < 4; ++ni)
        acc[mi][ni] = __builtin_amdgcn_mfma_f32_16x16x32_bf16(af[mi], bfr[ni], acc[mi][ni], 0, 0, 0);
    __syncthreads();
    cur ^= 1;
  }

#pragma unroll
  for (int mi = 0; mi < 4; ++mi)
#pragma unroll
    for (int ni = 0; ni < 4; ++ni)
#pragma unroll
      for (int r = 0; r < 4; ++r) {
        int m = m0 + wm + mi * 16 + lh * 4 + r;
        int n = n0 + wn + ni * 16 + lr;
        float vv = acc[mi][ni][r];
        if (MODE == 0) {
          int which = n >> 9, c9 = n & 511, hh = c9 >> 6, dh = c9 & 63;
          int b = m >> 11, s = m & 2047;
          size_t o = (size_t)((b * 8 + hh) * 2048 + s) * 64 + dh;
          if (which == 0) {
            __bf16 hv = (__bf16)vv;
            qh[o] = hv;
            ql[o] = (__bf16)(vv - (float)hv);
          } else if (which == 1) {
            ko[o] = (__bf16)vv;
          } else {
            vo[o] = (__bf16)vv;
          }
        } else {
          fo[(size_t)m * 512 + n] = vv;
        }
      }
}

// ---------- transpose V to [bh][dh][s], with per-64 k-column permutation ----------
// dest 4-col group d2 for source group c2:  k = 32a+16u+4m+v  ->  p = 32a+8m+4u+v
__global__ void k_transv(const __bf16* __restrict__ v, __bf16* __restrict__ vt) {
  __shared__ __bf16 t[64][72];
  int bh = blockIdx.y, s0 = blockIdx.x * 64, tid = threadIdx.x;
  const __bf16* src = v + (size_t)bh * SEQ * 64;
  __bf16* dst = vt + (size_t)bh * 64 * SEQ;
#pragma unroll
  for (int c = 0; c < 2; ++c) {
    int i = c * 256 + tid, row = i >> 3, col = (i & 7) * 8;
    *(bf16x8*)&t[row][col] = *(const bf16x8*)&src[(size_t)(s0 + row) * 64 + col];
  }
  __syncthreads();
#pragma unroll
  for (int c = 0; c < 2; ++c) {
    int i = c * 256 + tid, dh = i >> 3, c8 = i & 7;
    bf16x4 o1, o2;
#pragma unroll
    for (int j = 0; j < 4; ++j) { o1[j] = t[c8 * 8 + j][dh]; o2[j] = t[c8 * 8 + 4 + j][dh]; }
    int c2a = 2 * c8, c2b = 2 * c8 + 1;
    int d2a = ((c2a >> 3) << 3) | ((c2a & 3) << 1) | ((c2a >> 2) & 1);
    int d2b = ((c2b >> 3) << 3) | ((c2b & 3) << 1) | ((c2b >> 2) & 1);
    *(bf16x4*)&dst[(size_t)dh * SEQ + s0 + 4 * d2a] = o1;
    *(bf16x4*)&dst[(size_t)dh * SEQ + s0 + 4 * d2b] = o2;
  }
}

// ---------- flash attention: swapped QK^T, register-resident P (k-permuted PV), defer-max ----------
__global__ __launch_bounds__(512) void k_attn(const __bf16* __restrict__ qhp,
                                              const __bf16* __restrict__ qlp,
                                              const __bf16* __restrict__ k,
                                              const __bf16* __restrict__ vt,
                                              const float* __restrict__ bias_tab,
                                              __bf16* __restrict__ ao) {
  __shared__ __align__(16) __bf16 Ks[2][64 * 64];
  __shared__ __align__(16) __bf16 Vs[2][64 * 64];
  __shared__ __align__(16) __bf16 Qs[128 * 64];   // Q staging only
  __shared__ float bias_s[2176];
  int tid = threadIdx.x, w = tid >> 6, l = tid & 63;
  int lr = l & 15, lh = l >> 4;
  int d = blockIdx.x;
  int bh = (d & 7) + ((d >> 3) & 3) * 8;
  int q0 = (d >> 5) * 128;
  int h = bh & 7, b = bh >> 3;
  const char* kbase = (const char*)(k + (size_t)bh * SEQ * 64);
  const char* vbase = (const char*)(vt + (size_t)bh * 64 * SEQ);

  for (int j = tid; j < 2176; j += 512)
    bias_s[j] = bias_tab[h * 4096 + (1920 - q0) + j];

  auto stageKV = [&](int kt, int buf) {
    const char* kb = kbase + (size_t)kt * 64 * 128;
    const char* vb = vbase + (size_t)kt * 128;
    int row = tid >> 3, colb = (tid & 7) * 16;
    gl_lds16(kb + row * 128 + (colb ^ swz(row)), (char*)&Ks[buf][0] + tid * 16);
    gl_lds16(vb + (size_t)row * 4096 + (colb ^ swz(row)), (char*)&Vs[buf][0] + tid * 16);
  };

  auto stageQ = [&](const __bf16* qsrc) {
    const char* qb = (const char*)(qsrc + (size_t)bh * SEQ * 64) + (size_t)q0 * 128;
#pragma unroll
    for (int c = 0; c < 2; ++c) {
      int i = c * 512 + tid;
      int row = i >> 3, colb = (i & 7) * 16;
      gl_lds16(qb + row * 128 + (colb ^ swz(row)), (char*)&Qs[0] + i * 16);
    }
  };

  bf16x8 qfh[2], qfl[2];
  int qrow = w * 16 + lr;
  const char* qread = (const char*)&Qs[0];

  stageQ(qhp);
  __syncthreads();
  qfh[0] = *(const bf16x8*)(qread + qrow * 128 + ((lh * 16) ^ swz(qrow)));
  qfh[1] = *(const bf16x8*)(qread + qrow * 128 + ((64 + lh * 16) ^ swz(qrow)));
  __syncthreads();
  stageQ(qlp);
  stageKV(0, 0);
  __syncthreads();
  qfl[0] = *(const bf16x8*)(qread + qrow * 128 + ((lh * 16) ^ swz(qrow)));
  qfl[1] = *(const bf16x8*)(qread + qrow * 128 + ((64 + lh * 16) ^ swz(qrow)));

  float m_run = -1e30f, l_run = 0.f;
  f32x4 zero4 = {0.f, 0.f, 0.f, 0.f};
  f32x4 oacc[4];
#pragma unroll
  for (int i = 0; i < 4; ++i) oacc[i] = zero4;

#pragma unroll 2
  for (int kt = 0; kt < 32; ++kt) {
    int cur = kt & 1;
    if (kt + 1 < 32) stageKV(kt + 1, cur ^ 1);
    const char* kb = (const char*)&Ks[cur][0];
    f32x4 sacc[4];
    __builtin_amdgcn_s_setprio(1);
#pragma unroll
    for (int t = 0; t < 4; ++t) {
      int row = t * 16 + lr;
      bf16x8 b0 = *(const bf16x8*)(kb + row * 128 + ((lh * 16) ^ swz(row)));
      bf16x8 b1 = *(const bf16x8*)(kb + row * 128 + ((64 + lh * 16) ^ swz(row)));
      f32x4 z = zero4;
      z = __builtin_amdgcn_mfma_f32_16x16x32_bf16(b0, qfh[0], z, 0, 0, 0);
      z = __builtin_amdgcn_mfma_f32_16x16x32_bf16(b1, qfh[1], z, 0, 0, 0);
      z = __builtin_amdgcn_mfma_f32_16x16x32_bf16(b0, qfl[0], z, 0, 0, 0);
      z = __builtin_amdgcn_mfma_f32_16x16x32_bf16(b1, qfl[1], z, 0, 0, 0);
      sacc[t] = z;
    }
    __builtin_amdgcn_s_setprio(0);
    // lane (lr,lh) reg (t,r): S[q = q0+w*16+lr][k = kt*64 + t*16 + lh*4 + r]
    float p[4][4];
    int jb = kt * 64 + lh * 4 + 127 - (w * 16 + lr);
    float mx = -1e30f;
#pragma unroll
    for (int t = 0; t < 4; ++t)
#pragma unroll
      for (int r = 0; r < 4; ++r) {
        float sv = sacc[t][r] + bias_s[jb + t * 16 + r];
        p[t][r] = sv;
        mx = fmaxf(mx, sv);
      }
    mx = fmaxf(mx, __shfl_xor(mx, 16));
    mx = fmaxf(mx, __shfl_xor(mx, 32));
    if (!__all(mx <= m_run + 8.0f)) {              // defer-max: rescale only on growth
      float mnew = fmaxf(m_run, mx);
      float sc = __expf(m_run - mnew);
      m_run = mnew;
      l_run *= sc;
#pragma unroll
      for (int r = 0; r < 4; ++r) {
        float scr = __shfl(sc, lh * 4 + r);        // sc of output row lh*4+r
#pragma unroll
        for (int ni = 0; ni < 4; ++ni) oacc[ni][r] *= scr;
      }
    }
    float rs = 0.f;
#pragma unroll
    for (int t = 0; t < 4; ++t)
#pragma unroll
      for (int r = 0; r < 4; ++r) {
        float pv = __expf(p[t][r] - m_run);
        p[t][r] = pv;
        rs += pv;
      }
    rs += __shfl_xor(rs, 16);
    rs += __shfl_xor(rs, 32);
    l_run += rs;
    // pack P in-register: pa0 slot(lh,e) holds k=16*(e/4)+4*lh+(e&3); V cols permuted to match
    uint32_t pk[4][2];
#pragma unroll
    for (int t = 0; t < 4; ++t) {
      asm("v_cvt_pk_bf16_f32 %0, %1, %2" : "=v"(pk[t][0]) : "v"(p[t][0]), "v"(p[t][1]));
      asm("v_cvt_pk_bf16_f32 %0, %1, %2" : "=v"(pk[t][1]) : "v"(p[t][2]), "v"(p[t][3]));
    }
    u32x4 A0 = {pk[0][0], pk[0][1], pk[1][0], pk[1][1]};
    u32x4 A1 = {pk[2][0], pk[2][1], pk[3][0], pk[3][1]};
    bf16x8 pa0 = __builtin_bit_cast(bf16x8, A0);
    bf16x8 pa1 = __builtin_bit_cast(bf16x8, A1);
    // PV
    {
      const char* vbr = (const char*)&Vs[cur][0];
      __builtin_amdgcn_s_setprio(1);
#pragma unroll
      for (int ni = 0; ni < 4; ++ni) {
        int vrow = ni * 16 + lr;
        bf16x8 v0 = *(const bf16x8*)(vbr + vrow * 128 + ((lh * 16) ^ swz(vrow)));
        bf16x8 v1 = *(const bf16x8*)(vbr + vrow * 128 + ((64 + lh * 16) ^ swz(vrow)));
        oacc[ni] = __builtin_amdgcn_mfma_f32_16x16x32_bf16(pa0, v0, oacc[ni], 0, 0, 0);
        oacc[ni] = __builtin_amdgcn_mfma_f32_16x16x32_bf16(pa1, v1, oacc[ni], 0, 0, 0);
      }
      __builtin_amdgcn_s_setprio(0);
    }
    __syncthreads();
  }

#pragma unroll
  for (int r = 0; r < 4; ++r) {
    float linv = 1.0f / __shfl(l_run, lh * 4 + r);
    int s = q0 + w * 16 + lh * 4 + r;
#pragma unroll
    for (int ni = 0; ni < 4; ++ni) {
      int dh = ni * 16 + lr;
      ao[((size_t)(b * 2048 + s)) * 512 + h * 64 + dh] = (__bf16)(oacc[ni][r] * linv);
    }
  }
}

extern "C" void kernel_launch(void* const* d_in, const int* in_sizes, int n_in,
                              void* d_out, int out_size, void* d_ws, size_t ws_size,
                              hipStream_t stream) {
  (void)in_sizes; (void)n_in; (void)out_size; (void)ws_size;
  const float* hs = (const float*)d_in[0];
  const float* Wq = (const float*)d_in[1];
  const float* Wk = (const float*)d_in[2];
  const float* Wv = (const float*)d_in[3];
  const float* Wo = (const float*)d_in[4];
  const float* rb = (const float*)d_in[5];
  char* ws = (char*)d_ws;
  __bf16* hs2    = (__bf16*)(ws + OFF_HS2);
  __bf16* wqkv2  = (__bf16*)(ws + OFF_WQKV2);
  __bf16* wo_t   = (__bf16*)(ws + OFF_WO);
  __bf16* qhb    = (__bf16*)(ws + OFF_QH);
  __bf16* qlb    = (__bf16*)(ws + OFF_QL);
  __bf16* kb     = (__bf16*)(ws + OFF_K);
  __bf16* vb     = (__bf16*)(ws + OFF_V);
  __bf16* vtb    = (__bf16*)(ws + OFF_VT);
  __bf16* aob    = (__bf16*)(ws + OFF_AO);
  float*  bias   = (float*)(ws + OFF_BIAS);

  k_cast_hs2<<<2048, 256, 0, stream>>>(hs, hs2);
  k_prep_w2<<<dim3(8, 8, 3), 256, 0, stream>>>(Wq, Wk, Wv, wqkv2);
  k_prep_wo<<<1024, 256, 0, stream>>>(Wo, wo_t);
  k_bias<<<128, 256, 0, stream>>>(rb, bias);
  k_gemm<0, 48, 1024, 1536><<<dim3(12, 64), 256, 0, stream>>>(hs2, wqkv2, qhb, qlb, kb, vb, nullptr);
  k_transv<<<dim3(32, 32), 256, 0, stream>>>(vb, vtb);
  k_attn<<<dim3(512), 512, 0, stream>>>(qhb, qlb, kb, vtb, bias, aob);
  k_gemm<1, 16, 512, 512><<<dim3(4, 64), 256, 0, stream>>>(aob, wo_t, nullptr, nullptr, nullptr, nullptr, (float*)d_out);
}